// Round 2
// baseline (513.628 us; speedup 1.0000x reference)
//
#include <hip/hip_runtime.h>
#include <math.h>

#define NBLK 1024
#define K 5
#define D 384
#define THREADS 256
#define GROUPS_PER_BLOCK (THREADS/16)   // 16 rows per block-iter
#define C1 (GROUPS_PER_BLOCK*K)         // 80 candidates per block
#define C2 (NBLK*K)                     // 5120 candidates total

__device__ __forceinline__ bool better(float v1, int r1, float v2, int r2) {
    // strictly larger value wins; on exact tie, smaller row index wins (jax top_k order)
    return (v1 > v2) || (v1 == v2 && r1 < r2);
}

__global__ __launch_bounds__(THREADS) void fused_sim_topk_kernel(
        const float* __restrict__ corpus, const float* __restrict__ q,
        float* __restrict__ bVals, int* __restrict__ bIdx,
        unsigned int* __restrict__ counter,
        float* __restrict__ out, int N) {
    __shared__ float qs[D];
    __shared__ float s_invq;
    __shared__ float cv[C1]; __shared__ int ci[C1];
    __shared__ float rv[THREADS]; __shared__ int ri[THREADS]; __shared__ int rs[THREADS];
    __shared__ bool amLast;

    // ---- per-block q staging + normalization (1.5 KB, L2-hot after block 0) ----
    float4* qs4 = (float4*)qs;
    if (threadIdx.x < D/4) qs4[threadIdx.x] = ((const float4*)q)[threadIdx.x];
    __syncthreads();
    if (threadIdx.x < 64) {
        float ss = 0.f;
        #pragma unroll
        for (int j = 0; j < 6; ++j) { float x = qs[threadIdx.x + 64*j]; ss += x*x; }
        #pragma unroll
        for (int m = 1; m < 64; m <<= 1) ss += __shfl_xor(ss, m);
        if (threadIdx.x == 0) s_invq = 1.0f / fmaxf(sqrtf(ss), 1e-12f);
    }
    __syncthreads();
    if (threadIdx.x < D/4) {
        float iv = s_invq;
        float4 v = qs4[threadIdx.x];
        v.x *= iv; v.y *= iv; v.z *= iv; v.w *= iv;
        qs4[threadIdx.x] = v;
    }
    __syncthreads();
    const float4* q4 = (const float4*)qs;

    const int lane16 = threadIdx.x & 15;
    const int group  = threadIdx.x >> 4;
    const int ggid   = blockIdx.x * GROUPS_PER_BLOCK + group;
    const int gcount = NBLK * GROUPS_PER_BLOCK;

    float tv[K]; int ti[K];
    #pragma unroll
    for (int i = 0; i < K; ++i) { tv[i] = -INFINITY; ti[i] = 0x7fffffff; }

    auto insert = [&](float sim, int r) {
        if (sim > tv[K-1]) {               // strict: equal keeps earlier row
            int j = K - 1;
            while (j > 0 && tv[j-1] < sim) { tv[j] = tv[j-1]; ti[j] = ti[j-1]; --j; }
            tv[j] = sim; ti[j] = r;
        }
    };

    // ---- main streaming loop, 2 rows per group-iter for MLP ----
    int row = ggid;
    for (; row + gcount < N; row += 2*gcount) {
        const int rowB = row + gcount;
        const float4* rA = (const float4*)(corpus + (size_t)row  * D);
        const float4* rB = (const float4*)(corpus + (size_t)rowB * D);
        float dotA = 0.f, nrmA = 0.f, dotB = 0.f, nrmB = 0.f;
        #pragma unroll
        for (int j = 0; j < 6; ++j) {
            float4 w  = q4[lane16 + 16*j];
            float4 xA = rA[lane16 + 16*j];
            float4 xB = rB[lane16 + 16*j];
            dotA += xA.x*w.x + xA.y*w.y + xA.z*w.z + xA.w*w.w;
            nrmA += xA.x*xA.x + xA.y*xA.y + xA.z*xA.z + xA.w*xA.w;
            dotB += xB.x*w.x + xB.y*w.y + xB.z*w.z + xB.w*w.w;
            nrmB += xB.x*xB.x + xB.y*xB.y + xB.z*xB.z + xB.w*xB.w;
        }
        #pragma unroll
        for (int m = 1; m < 16; m <<= 1) {
            dotA += __shfl_xor(dotA, m); nrmA += __shfl_xor(nrmA, m);
            dotB += __shfl_xor(dotB, m); nrmB += __shfl_xor(nrmB, m);
        }
        if (lane16 == 0) {
            float simA = dotA / fmaxf(sqrtf(nrmA), 1e-12f);
            simA = fmaxf(simA, 1e-6f);
            if (simA != simA) simA = 0.f;
            insert(simA, row);
            float simB = dotB / fmaxf(sqrtf(nrmB), 1e-12f);
            simB = fmaxf(simB, 1e-6f);
            if (simB != simB) simB = 0.f;
            insert(simB, rowB);
        }
    }
    if (row < N) {
        const float4* rA = (const float4*)(corpus + (size_t)row * D);
        float dot = 0.f, nrm = 0.f;
        #pragma unroll
        for (int j = 0; j < 6; ++j) {
            float4 w = q4[lane16 + 16*j];
            float4 x = rA[lane16 + 16*j];
            dot += x.x*w.x + x.y*w.y + x.z*w.z + x.w*w.w;
            nrm += x.x*x.x + x.y*x.y + x.z*x.z + x.w*x.w;
        }
        #pragma unroll
        for (int m = 1; m < 16; m <<= 1) { dot += __shfl_xor(dot, m); nrm += __shfl_xor(nrm, m); }
        if (lane16 == 0) {
            float sim = dot / fmaxf(sqrtf(nrm), 1e-12f);
            sim = fmaxf(sim, 1e-6f);
            if (sim != sim) sim = 0.f;
            insert(sim, row);
        }
    }

    // ---- block-level top-K over the 16 leaders' sorted lists ----
    if (lane16 == 0) {
        #pragma unroll
        for (int i = 0; i < K; ++i) { cv[group*K + i] = tv[i]; ci[group*K + i] = ti[i]; }
    }
    __syncthreads();

    for (int r = 0; r < K; ++r) {
        float bv = -INFINITY; int bi = 0x7fffffff; int bslot = -1;
        for (int c = threadIdx.x; c < C1; c += THREADS)
            if (better(cv[c], ci[c], bv, bi)) { bv = cv[c]; bi = ci[c]; bslot = c; }
        rv[threadIdx.x] = bv; ri[threadIdx.x] = bi; rs[threadIdx.x] = bslot;
        __syncthreads();
        for (int s = THREADS/2; s > 0; s >>= 1) {
            if (threadIdx.x < s) {
                if (better(rv[threadIdx.x+s], ri[threadIdx.x+s], rv[threadIdx.x], ri[threadIdx.x])) {
                    rv[threadIdx.x] = rv[threadIdx.x+s];
                    ri[threadIdx.x] = ri[threadIdx.x+s];
                    rs[threadIdx.x] = rs[threadIdx.x+s];
                }
            }
            __syncthreads();
        }
        if (threadIdx.x == 0) {
            bVals[blockIdx.x*K + r] = rv[0];
            bIdx [blockIdx.x*K + r] = ri[0];
            if (rs[0] >= 0) cv[rs[0]] = -INFINITY;
        }
        __syncthreads();
    }

    // ---- last block to finish does the global top-K (release/acquire via fence+atomic) ----
    __threadfence();
    if (threadIdx.x == 0) {
        unsigned int v = atomicAdd(counter, 1u);
        amLast = (v == (unsigned int)(NBLK - 1));
    }
    __syncthreads();
    if (!amLast) return;
    __threadfence();   // acquire: all blocks' bVals/bIdx now visible

    for (int r = 0; r < K; ++r) {
        float bv = -INFINITY; int bi = 0x7fffffff; int bslot = -1;
        for (int c = threadIdx.x; c < C2; c += THREADS) {
            float v = bVals[c]; int idx = bIdx[c];
            if (better(v, idx, bv, bi)) { bv = v; bi = idx; bslot = c; }
        }
        rv[threadIdx.x] = bv; ri[threadIdx.x] = bi; rs[threadIdx.x] = bslot;
        __syncthreads();
        for (int s = THREADS/2; s > 0; s >>= 1) {
            if (threadIdx.x < s) {
                if (better(rv[threadIdx.x+s], ri[threadIdx.x+s], rv[threadIdx.x], ri[threadIdx.x])) {
                    rv[threadIdx.x] = rv[threadIdx.x+s];
                    ri[threadIdx.x] = ri[threadIdx.x+s];
                    rs[threadIdx.x] = rs[threadIdx.x+s];
                }
            }
            __syncthreads();
        }
        if (threadIdx.x == 0) {
            out[r]     = rv[0];
            out[K + r] = (float)ri[0];        // indices output read back as f32
            if (rs[0] >= 0) bVals[rs[0]] = -INFINITY;
            __threadfence_block();
        }
        __syncthreads();
    }
}

extern "C" void kernel_launch(void* const* d_in, const int* in_sizes, int n_in,
                              void* d_out, int out_size, void* d_ws, size_t ws_size,
                              hipStream_t stream) {
    const float* q      = (const float*)d_in[0];
    const float* corpus = (const float*)d_in[1];
    const int N = in_sizes[1] / D;

    char* ws = (char*)d_ws;
    unsigned int* counter = (unsigned int*)ws;           // 4 B @ ws+0
    float* bVals = (float*)(ws + 256);                   // NBLK*K floats
    int*   bIdx  = (int*)  (ws + 256 + NBLK*K*4);        // NBLK*K ints

    float* out = (float*)d_out;

    hipMemsetAsync(counter, 0, sizeof(unsigned int), stream);
    fused_sim_topk_kernel<<<NBLK, THREADS, 0, stream>>>(
        corpus, q, bVals, bIdx, counter, out, N);
}

// Round 4
// 258.848 us; speedup vs baseline: 1.9843x; 1.9843x over previous
//
#include <hip/hip_runtime.h>
#include <math.h>

#define NBLK 1024
#define K 5
#define D 384
#define THREADS 256
#define GROUPS_PER_BLOCK (THREADS/16)   // 16 rows per block-iter
#define C1 (GROUPS_PER_BLOCK*K)         // 80 candidates per block
#define C2 (NBLK*K)                     // 5120 candidates total

typedef float f32x4 __attribute__((ext_vector_type(4)));

__device__ __forceinline__ bool better(float v1, int r1, float v2, int r2) {
    // strictly larger value wins; on exact tie, smaller row index wins (jax top_k order)
    return (v1 > v2) || (v1 == v2 && r1 < r2);
}

// ---- kernel 1: per-row cosine sim + per-block top-K (q normalized per-block) ----
__global__ __launch_bounds__(THREADS) void sim_topk_kernel(
        const float* __restrict__ corpus, const float* __restrict__ q,
        float* __restrict__ bVals, int* __restrict__ bIdx, int N) {
    __shared__ float qs[D];
    __shared__ float s_invq;

    // stage q, compute 1/||q|| in-block (1.5 KB read, L2-hot after first blocks)
    f32x4* qs4 = (f32x4*)qs;
    if (threadIdx.x < D/4) qs4[threadIdx.x] = ((const f32x4*)q)[threadIdx.x];
    __syncthreads();
    if (threadIdx.x < 64) {
        float ss = 0.f;
        #pragma unroll
        for (int j = 0; j < 6; ++j) { float x = qs[threadIdx.x + 64*j]; ss += x*x; }
        #pragma unroll
        for (int m = 1; m < 64; m <<= 1) ss += __shfl_xor(ss, m);
        if (threadIdx.x == 0) s_invq = 1.0f / fmaxf(sqrtf(ss), 1e-12f);
    }
    __syncthreads();

    const int lane16 = threadIdx.x & 15;
    const int group  = threadIdx.x >> 4;
    const int ggid   = blockIdx.x * GROUPS_PER_BLOCK + group;
    const int gcount = NBLK * GROUPS_PER_BLOCK;

    // hoist this lane's q fragment into registers (24 VGPRs), pre-scaled by 1/||q||
    const float iv = s_invq;
    f32x4 w[6];
    #pragma unroll
    for (int j = 0; j < 6; ++j) w[j] = qs4[lane16 + 16*j] * iv;

    float tv[K]; int ti[K];
    #pragma unroll
    for (int i = 0; i < K; ++i) { tv[i] = -INFINITY; ti[i] = 0x7fffffff; }

    for (int row = ggid; row < N; row += gcount) {
        const f32x4* r4 = (const f32x4*)(corpus + (size_t)row * D);
        float dot = 0.f, nrm = 0.f;
        #pragma unroll
        for (int j = 0; j < 6; ++j) {
            f32x4 x = __builtin_nontemporal_load(&r4[lane16 + 16*j]);
            dot += x.x*w[j].x + x.y*w[j].y + x.z*w[j].z + x.w*w[j].w;
            nrm += x.x*x.x + x.y*x.y + x.z*x.z + x.w*x.w;
        }
        #pragma unroll
        for (int m = 1; m < 16; m <<= 1) {
            dot += __shfl_xor(dot, m);
            nrm += __shfl_xor(nrm, m);
        }
        if (lane16 == 0) {
            float sim = dot / fmaxf(sqrtf(nrm), 1e-12f);
            sim = fmaxf(sim, 1e-6f);           // clamp(min=1e-6); NaN propagates
            if (sim != sim) sim = 0.f;         // nan_to_num
            if (sim > tv[K-1]) {               // strict: equal keeps earlier row
                int j = K - 1;
                while (j > 0 && tv[j-1] < sim) { tv[j] = tv[j-1]; ti[j] = ti[j-1]; --j; }
                tv[j] = sim; ti[j] = row;
            }
        }
    }

    // block-level top-K over the 16 leaders' sorted lists
    __shared__ float cv[C1]; __shared__ int ci[C1];
    __shared__ float rv[THREADS]; __shared__ int ri[THREADS]; __shared__ int rs[THREADS];
    if (lane16 == 0) {
        #pragma unroll
        for (int i = 0; i < K; ++i) { cv[group*K + i] = tv[i]; ci[group*K + i] = ti[i]; }
    }
    __syncthreads();

    for (int r = 0; r < K; ++r) {
        float bv = -INFINITY; int bi = 0x7fffffff; int bslot = -1;
        for (int c = threadIdx.x; c < C1; c += THREADS)
            if (better(cv[c], ci[c], bv, bi)) { bv = cv[c]; bi = ci[c]; bslot = c; }
        rv[threadIdx.x] = bv; ri[threadIdx.x] = bi; rs[threadIdx.x] = bslot;
        __syncthreads();
        for (int s = THREADS/2; s > 0; s >>= 1) {
            if (threadIdx.x < s) {
                if (better(rv[threadIdx.x+s], ri[threadIdx.x+s], rv[threadIdx.x], ri[threadIdx.x])) {
                    rv[threadIdx.x] = rv[threadIdx.x+s];
                    ri[threadIdx.x] = ri[threadIdx.x+s];
                    rs[threadIdx.x] = rs[threadIdx.x+s];
                }
            }
            __syncthreads();
        }
        if (threadIdx.x == 0) {
            bVals[blockIdx.x*K + r] = rv[0];
            bIdx [blockIdx.x*K + r] = ri[0];
            if (rs[0] >= 0) cv[rs[0]] = -INFINITY;
        }
        __syncthreads();
    }
}

// ---- kernel 2: global top-K over block candidates ----
__global__ __launch_bounds__(THREADS) void final_topk_kernel(
        const float* __restrict__ bVals, const int* __restrict__ bIdx,
        float* __restrict__ out, int nC) {
    __shared__ float cv[C2]; __shared__ int ci[C2];
    __shared__ float rv[THREADS]; __shared__ int ri[THREADS]; __shared__ int rs[THREADS];
    for (int c = threadIdx.x; c < nC; c += THREADS) { cv[c] = bVals[c]; ci[c] = bIdx[c]; }
    __syncthreads();

    for (int r = 0; r < K; ++r) {
        float bv = -INFINITY; int bi = 0x7fffffff; int bslot = -1;
        for (int c = threadIdx.x; c < nC; c += THREADS)
            if (better(cv[c], ci[c], bv, bi)) { bv = cv[c]; bi = ci[c]; bslot = c; }
        rv[threadIdx.x] = bv; ri[threadIdx.x] = bi; rs[threadIdx.x] = bslot;
        __syncthreads();
        for (int s = THREADS/2; s > 0; s >>= 1) {
            if (threadIdx.x < s) {
                if (better(rv[threadIdx.x+s], ri[threadIdx.x+s], rv[threadIdx.x], ri[threadIdx.x])) {
                    rv[threadIdx.x] = rv[threadIdx.x+s];
                    ri[threadIdx.x] = ri[threadIdx.x+s];
                    rs[threadIdx.x] = rs[threadIdx.x+s];
                }
            }
            __syncthreads();
        }
        if (threadIdx.x == 0) {
            out[r]     = rv[0];
            out[K + r] = (float)ri[0];    // indices output read back as f32
            if (rs[0] >= 0) cv[rs[0]] = -INFINITY;
        }
        __syncthreads();
    }
}

extern "C" void kernel_launch(void* const* d_in, const int* in_sizes, int n_in,
                              void* d_out, int out_size, void* d_ws, size_t ws_size,
                              hipStream_t stream) {
    const float* q      = (const float*)d_in[0];
    const float* corpus = (const float*)d_in[1];
    const int N = in_sizes[1] / D;

    char* ws = (char*)d_ws;
    float* bVals = (float*)(ws + 256);               // NBLK*K floats
    int*   bIdx  = (int*)  (ws + 256 + NBLK*K*4);    // NBLK*K ints

    float* out = (float*)d_out;

    sim_topk_kernel<<<NBLK, THREADS, 0, stream>>>(corpus, q, bVals, bIdx, N);
    final_topk_kernel<<<1, THREADS, 0, stream>>>(bVals, bIdx, out, NBLK*K);
}